// Round 1
// baseline (170.966 us; speedup 1.0000x reference)
//
#include <hip/hip_runtime.h>
#include <stdint.h>

// SelfAttention1D: B=8, C=256, L=2048, D=32, fp32 in/out, bf16 MFMA compute.
//
// ws layout (bytes):
//   Wh  @ 0x000000 : bf16 [320][256]   rows 0-31 Wq, 32-63 Wk, 64-319 Wv (160 KB)
//   Qh  @ 0x040000 : bf16 [B][L][32]   Q pre-scaled by (1/sqrt(D))*log2(e) (1 MB)
//   Kth @ 0x140000 : bf16 [B][L][32]   K^T, d-contiguous (1 MB)
//   Vh  @ 0x240000 : bf16 [B][256][L]  V, j-contiguous (8 MB)
// total 10.25 MB

#define BB 8
#define CC 256
#define LL 2048
#define DD 32

typedef unsigned short u16;
typedef __attribute__((ext_vector_type(8))) short short8;
typedef __attribute__((ext_vector_type(4))) float f32x4;

#define SCALE_LOG2E 0.2550348612f

static __device__ __forceinline__ uint32_t pack2bf16(float hi, float lo) {
    return (__float_as_uint(hi) & 0xFFFF0000u) | (__float_as_uint(lo) >> 16);
}

static __device__ __forceinline__ float fexp2(float v) {
#if __has_builtin(__builtin_amdgcn_exp2f)
    return __builtin_amdgcn_exp2f(v);
#else
    return exp2f(v);
#endif
}

static __device__ __forceinline__ float frcp(float v) {
#if __has_builtin(__builtin_amdgcn_rcpf)
    return __builtin_amdgcn_rcpf(v);
#else
    return 1.0f / v;
#endif
}

// ---------------- kernel 1: W -> bf16 ----------------
__global__ __launch_bounds__(256) void prep_w_kernel(
    const float* __restrict__ Wq, const float* __restrict__ Wk,
    const float* __restrict__ Wv, u16* __restrict__ Wh)
{
    int idx = blockIdx.x * 256 + threadIdx.x;     // 320 rows * 64 float4
    int r = idx >> 6;
    int c4 = (idx & 63) << 2;
    const float* src;
    if (r < 32)       src = Wq + (size_t)r * CC + c4;
    else if (r < 64)  src = Wk + (size_t)(r - 32) * CC + c4;
    else              src = Wv + (size_t)(r - 64) * CC + c4;
    float4 v = *(const float4*)src;
    uint2 o;
    o.x = pack2bf16(v.y, v.x);
    o.y = pack2bf16(v.w, v.z);
    *(uint2*)(Wh + (size_t)r * CC + c4) = o;
}

// ---------------- kernel 2: QKV projection ----------------
// grid 512 = 8 b x 64 l-tiles(32), 512 thr (8 waves), 2 blocks/CU.
__global__ __launch_bounds__(512, 2) void proj_kernel(
    const float* __restrict__ x, const u16* __restrict__ Wh,
    const float* __restrict__ bq, const float* __restrict__ bk,
    const float* __restrict__ bv,
    u16* __restrict__ Qh, u16* __restrict__ Kth, u16* __restrict__ Vh)
{
    __shared__ u16 xls[32 * 264];        // 16.9 KB
    const int blk = blockIdx.x;
    const int b = blk & 7;
    const int l0 = (blk >> 3) << 5;
    const int tid = threadIdx.x;
    const int w = tid >> 6;
    const int lane = tid & 63;
    const int ln = lane & 15;
    const int q = lane >> 4;

#pragma unroll
    for (int cc = 0; cc < 4; ++cc) {
        const int c = cc * 64 + (tid >> 3);
        const int l4 = (tid & 7) * 4;
        const float4 v = *(const float4*)(x + ((size_t)(b * CC + c)) * LL + l0 + l4);
        xls[(l4 + 0) * 264 + c] = (u16)(__float_as_uint(v.x) >> 16);
        xls[(l4 + 1) * 264 + c] = (u16)(__float_as_uint(v.y) >> 16);
        xls[(l4 + 2) * 264 + c] = (u16)(__float_as_uint(v.z) >> 16);
        xls[(l4 + 3) * 264 + c] = (u16)(__float_as_uint(v.w) >> 16);
    }
    __syncthreads();

    const int wl = w & 1;
    const int wm = w >> 1;               // 0..3 -> 80 rows each
    const int mbase = wm * 80;
    const int l = l0 + wl * 16 + ln;

    f32x4 acc[5];
#pragma unroll
    for (int i = 0; i < 5; ++i) acc[i] = (f32x4){0.f, 0.f, 0.f, 0.f};

#pragma unroll
    for (int c0 = 0; c0 < CC; c0 += 32) {
        const short8 bf = *(const short8*)(&xls[(wl * 16 + ln) * 264 + c0 + q * 8]);
#pragma unroll
        for (int mt = 0; mt < 5; ++mt) {
            const short8 af = *(const short8*)(Wh + (size_t)(mbase + mt * 16 + ln) * CC + c0 + q * 8);
            acc[mt] = __builtin_amdgcn_mfma_f32_16x16x32_bf16(af, bf, acc[mt], 0, 0, 0);
        }
    }

#pragma unroll
    for (int mt = 0; mt < 5; ++mt) {
        const int rg = mbase + mt * 16 + q * 4;   // global output row
        if (rg < 32) {                   // Q rows, pre-scaled
            float v0 = (acc[mt][0] + bq[rg + 0]) * SCALE_LOG2E;
            float v1 = (acc[mt][1] + bq[rg + 1]) * SCALE_LOG2E;
            float v2 = (acc[mt][2] + bq[rg + 2]) * SCALE_LOG2E;
            float v3 = (acc[mt][3] + bq[rg + 3]) * SCALE_LOG2E;
            uint2 o; o.x = pack2bf16(v1, v0); o.y = pack2bf16(v3, v2);
            *(uint2*)(Qh + ((size_t)(b * LL) + l) * DD + rg) = o;
        } else if (rg < 64) {            // K rows
            const int rk = rg - 32;
            float v0 = acc[mt][0] + bk[rk + 0];
            float v1 = acc[mt][1] + bk[rk + 1];
            float v2 = acc[mt][2] + bk[rk + 2];
            float v3 = acc[mt][3] + bk[rk + 3];
            uint2 o; o.x = pack2bf16(v1, v0); o.y = pack2bf16(v3, v2);
            *(uint2*)(Kth + ((size_t)(b * LL) + l) * DD + rk) = o;
        } else {                         // V rows -> Vh[b][c][l]
            const int cv = rg - 64;
#pragma unroll
            for (int rr = 0; rr < 4; ++rr) {
                const float v = acc[mt][rr] + bv[cv + rr];
                Vh[((size_t)(b * CC) + cv + rr) * LL + l] = (u16)(__float_as_uint(v) >> 16);
            }
        }
    }
}

// ---------------- kernel 3: fused attention (c-sliced waves, shared P) ----------------
// grid 512 = (b = blk&7 -> XCD L2 affinity) x (i-tile 32). 512 thr (8 waves),
// __launch_bounds__(512,4) -> 2 blocks/CU = 4 waves/SIMD (2x prior occupancy).
// Per 128-j iter: each wave computes a 16-j slice of S^T = K.Q^T (2 MFMA),
// exp2, writes shared P[32 i][128 j] (double-buffered, ONE barrier/iter);
// then PV over its PRIVATE 32-c slice: oacc[2][2] += V.P^T (16 MFMA).
// No obuf, no O cross-wave reduction. l partials reduced via 1KB lbuf.
#define PJ 136   // P row stride in u16: 272 B (odd dword multiple -> spread banks)

__global__ __launch_bounds__(512, 4) void attn_kernel(
    const u16* __restrict__ Qh, const u16* __restrict__ Kth,
    const u16* __restrict__ Vh, const float* __restrict__ x,
    const float* __restrict__ gamma, float* __restrict__ out)
{
    __shared__ __attribute__((aligned(16))) u16 pbuf[2][32][PJ]; // 17.4 KB
    __shared__ float lbuf[8][32];                                // 1 KB

    const int blk = blockIdx.x;
    const int b = blk & 7;
    const int i0 = (blk >> 3) << 5;      // i-tile of 32
    const int tid = threadIdx.x;
    const int w = tid >> 6;              // 0..7: j-slice (S) / c-slice (PV) owner
    const int lane = tid & 63;
    const int ln = lane & 15;
    const int q = lane >> 4;

    const u16* Qb = Qh + ((size_t)(b * LL) + i0) * DD;
    const u16* Kb = Kth + ((size_t)(b * LL) + w * 16 + ln) * DD + q * 8;
    const u16* Vb = Vh + ((size_t)(b * CC) + w * 32) * LL;

    short8 qf[2];
#pragma unroll
    for (int it = 0; it < 2; ++it)
        qf[it] = *(const short8*)(Qb + (size_t)(it * 16 + ln) * DD + q * 8);

    const f32x4 zf = {0.f, 0.f, 0.f, 0.f};
    f32x4 oacc[2][2];                    // [ct][it] = 16 VGPRs
#pragma unroll
    for (int a = 0; a < 2; ++a)
#pragma unroll
        for (int c = 0; c < 2; ++c) oacc[a][c] = zf;
    float lsum[2] = {0.f, 0.f};

    // K prefetch for iter 0 (wave's own 16-j slice)
    short8 kf = *(const short8*)(Kb);

    for (int n = 0; n < 16; ++n) {
        const int jb = n * 128;

        // V loads for THIS iter (consumed after S + barrier -> latency hidden)
        short8 vf[2][4];
#pragma unroll
        for (int ct = 0; ct < 2; ++ct)
#pragma unroll
            for (int kk = 0; kk < 4; ++kk)
                vf[ct][kk] = *(const short8*)(Vb + (size_t)(ct * 16 + ln) * LL + jb + kk * 32 + q * 8);
        // K prefetch for next iter
        const short8 kn = *(const short8*)(Kb + (size_t)((n < 15 ? n + 1 : n) * 128) * DD);

        // ---- S phase: wave's 16-j slice, exp2, write shared P[cur] ----
        u16* ps = &pbuf[n & 1][0][0];
#pragma unroll
        for (int it = 0; it < 2; ++it) {
            const f32x4 st = __builtin_amdgcn_mfma_f32_16x16x32_bf16(kf, qf[it], zf, 0, 0, 0);
            const float e0 = fexp2(st[0]), e1 = fexp2(st[1]);
            const float e2 = fexp2(st[2]), e3 = fexp2(st[3]);
            lsum[it] += (e0 + e1) + (e2 + e3);
            uint2 d; d.x = pack2bf16(e1, e0); d.y = pack2bf16(e3, e2);
            *(uint2*)(&ps[(it * 16 + ln) * PJ + w * 16 + q * 4]) = d;
        }
        __syncthreads();                 // P[cur] complete; prev buffer free

        // ---- PV: O += V.P^T over exclusive 32-c slice, full 128 j ----
        __builtin_amdgcn_s_setprio(1);
#pragma unroll
        for (int kk = 0; kk < 4; ++kk) {
            const short8 pf0 = *(const short8*)(&ps[(size_t)ln * PJ + kk * 32 + q * 8]);
            const short8 pf1 = *(const short8*)(&ps[(size_t)(16 + ln) * PJ + kk * 32 + q * 8]);
#pragma unroll
            for (int ct = 0; ct < 2; ++ct) {
                oacc[ct][0] = __builtin_amdgcn_mfma_f32_16x16x32_bf16(vf[ct][kk], pf0, oacc[ct][0], 0, 0, 0);
                oacc[ct][1] = __builtin_amdgcn_mfma_f32_16x16x32_bf16(vf[ct][kk], pf1, oacc[ct][1], 0, 0, 0);
            }
        }
        __builtin_amdgcn_s_setprio(0);
        kf = kn;
    }

    // ---- l: reduce over q within wave; publish per-wave j-slice partials ----
#pragma unroll
    for (int it = 0; it < 2; ++it) {
        float s = lsum[it];
        s += __shfl_xor(s, 16);
        s += __shfl_xor(s, 32);
        lsum[it] = s;
    }
    if (q == 0) {
        lbuf[w][ln] = lsum[0];
        lbuf[w][16 + ln] = lsum[1];
    }
    __syncthreads();

    float linv[2];
#pragma unroll
    for (int it = 0; it < 2; ++it) {
        float s = 0.f;
#pragma unroll
        for (int w8 = 0; w8 < 8; ++w8) s += lbuf[w8][it * 16 + ln];
        linv[it] = frcp(s);
    }

    // ---- finalize: out = gamma * O/l + x (direct from regs, 64B i-segments) ----
    const float g = gamma[0];
#pragma unroll
    for (int ct = 0; ct < 2; ++ct)
#pragma unroll
        for (int it = 0; it < 2; ++it) {
#pragma unroll
            for (int r = 0; r < 4; ++r) {
                const int c = w * 32 + ct * 16 + q * 4 + r;
                const size_t idx = ((size_t)(b * CC + c)) * LL + i0 + it * 16 + ln;
                out[idx] = g * (oacc[ct][it][r] * linv[it]) + x[idx];
            }
        }
}

// ---------------- launcher ----------------
extern "C" void kernel_launch(void* const* d_in, const int* in_sizes, int n_in,
                              void* d_out, int out_size, void* d_ws, size_t ws_size,
                              hipStream_t stream)
{
    const float* x     = (const float*)d_in[0];
    const float* Wq    = (const float*)d_in[1];
    const float* bq    = (const float*)d_in[2];
    const float* Wk    = (const float*)d_in[3];
    const float* bk    = (const float*)d_in[4];
    const float* Wv    = (const float*)d_in[5];
    const float* bv    = (const float*)d_in[6];
    const float* gamma = (const float*)d_in[7];
    float* out = (float*)d_out;

    uint8_t* ws = (uint8_t*)d_ws;
    u16* Wh  = (u16*)(ws + 0x000000);
    u16* Qh  = (u16*)(ws + 0x040000);
    u16* Kth = (u16*)(ws + 0x140000);
    u16* Vh  = (u16*)(ws + 0x240000);

    prep_w_kernel<<<80, 256, 0, stream>>>(Wq, Wk, Wv, Wh);
    proj_kernel<<<512, 512, 0, stream>>>(x, Wh, bq, bk, bv, Qh, Kth, Vh);
    attn_kernel<<<512, 512, 0, stream>>>(Qh, Kth, Vh, x, gamma, out);
}